// Round 7
// baseline (319.465 us; speedup 1.0000x reference)
//
#include <hip/hip_runtime.h>
#include <math.h>

#define B_ 32
#define T_ 1024
#define D_ 512
#define U_ 64
#define TS_ 4          // t-reduction split in K1
#define TH_ (T_/TS_)   // 256
#define TC_ 32         // K1 t-chunk staged in LDS
#define NC_ (TH_/TC_)  // 8 chunks
#define TT_ 64         // K2 t-tile
#define SR_ 10.0f
#define EPS_ 1e-7f

typedef __attribute__((ext_vector_type(8))) short bf16x8;
typedef __attribute__((ext_vector_type(4))) float f32x4;

#define LSTRIDE 40     // ushorts per LDS row; uint stride 20: write group=(5*col+tq)&7 even, b128-aligned

__device__ __forceinline__ uint pack_hi2(float e, float o) {
    return (__float_as_uint(e) >> 16) | (__float_as_uint(o) & 0xffff0000u);
}
__device__ __forceinline__ float hi_part(float v) {
    return __uint_as_float(__float_as_uint(v) & 0xffff0000u);
}
// build hi/lo uint4 from 8 floats (4 t-pairs / d-pairs)
__device__ __forceinline__ void pack8(const float* v, uint4& hv, uint4& lv) {
    hv.x = pack_hi2(v[0], v[1]); hv.y = pack_hi2(v[2], v[3]);
    hv.z = pack_hi2(v[4], v[5]); hv.w = pack_hi2(v[6], v[7]);
    lv.x = pack_hi2(v[0]-hi_part(v[0]), v[1]-hi_part(v[1]));
    lv.y = pack_hi2(v[2]-hi_part(v[2]), v[3]-hi_part(v[3]));
    lv.z = pack_hi2(v[4]-hi_part(v[4]), v[5]-hi_part(v[5]));
    lv.w = pack_hi2(v[6]-hi_part(v[6]), v[7]-hi_part(v[7]));
}

// ---------------------------------------------------------------------------
// K1 (MFMA): per (b, d-tile 64, t-quarter):
//   P[ts][b][0][d][u] += sum_t x1*w3 + x2*w2 ; P[ts][b][1][d][u] += x1*w2 + x2*w3
// bf16-split 3-term emulation. T14 staging order kept (issue early/write late).
// STAGING WRITES ARE uint4 (b128): addr_u = col*20 + 4*tq, 16B-aligned,
// group (5*col+tq)&7 spreads 64 lanes over 8 groups evenly -> conflict-free.
// (Old per-uint writes: bank 20*l mod 32 -> 8-way conflict; the R2-R6 k1 cost.)
// ---------------------------------------------------------------------------
__global__ __launch_bounds__(256, 3) void k1_partials(
    const float* __restrict__ x1, const float* __restrict__ x2,
    const float* __restrict__ w2, const float* __restrict__ w3,
    float* __restrict__ P)
{
    __shared__ ushort lds[8][64*LSTRIDE];  // x1h,x1l,x2h,x2l,w2h,w2l,w3h,w3l (40 KiB)

    const int dt  = blockIdx.x;       // 0..7
    const int ts  = blockIdx.y;       // 0..TS_-1
    const int b   = blockIdx.z;       // 0..31
    const int d0  = dt * 64;
    const int tid = threadIdx.x;
    const int lane = tid & 63;
    const int wid  = tid >> 6;        // 0..3
    const int wd   = wid & 1;         // d-half (32 rows)
    const int wu   = wid >> 1;        // u-half (32 cols)
    const int lr   = lane & 15;       // frag row/col within 16
    const int lg   = lane >> 4;       // k-group 0..3
    const int col  = tid & 63;        // staging feature column
    const int tq   = tid >> 6;        // staging t-subrange (8 t each)

    f32x4 acc1[2][2], acc2[2][2];
    const f32x4 z = {0.f, 0.f, 0.f, 0.f};
    #pragma unroll
    for (int mi = 0; mi < 2; ++mi)
        #pragma unroll
        for (int ni = 0; ni < 2; ++ni) { acc1[mi][ni] = z; acc2[mi][ni] = z; }

    const size_t xb = (size_t)b * T_ * D_;
    const int widx = col*(LSTRIDE/2) + 4*tq;   // uint4-aligned staging slot

    float stg[4][8];   // staged next-chunk values (held across MFMA phase)

    // ---- issue + write chunk 0
    {
        const int tb = ts*TH_ + 8*tq;
        const float* ga[4] = { x1 + xb + (size_t)tb*D_ + d0 + col,
                               x2 + xb + (size_t)tb*D_ + d0 + col,
                               w2 + (size_t)tb*U_ + col,
                               w3 + (size_t)tb*U_ + col };
        const int stra[4] = { D_, D_, U_, U_ };
        #pragma unroll
        for (int a = 0; a < 4; ++a)
            #pragma unroll
            for (int j = 0; j < 8; ++j) stg[a][j] = ga[a][(size_t)j * stra[a]];
    }
    #pragma unroll
    for (int a = 0; a < 4; ++a) {
        uint4 hv, lv;
        pack8(stg[a], hv, lv);
        *(uint4*)&((uint*)lds[a*2  ])[widx] = hv;
        *(uint4*)&((uint*)lds[a*2+1])[widx] = lv;
    }
    __syncthreads();

    for (int c = 0; c < NC_; ++c) {
        // ---- issue next chunk's loads (latency hides under MFMA below)
        if (c+1 < NC_) {
            const int tb = ts*TH_ + (c+1)*TC_ + 8*tq;
            const float* ga[4] = { x1 + xb + (size_t)tb*D_ + d0 + col,
                                   x2 + xb + (size_t)tb*D_ + d0 + col,
                                   w2 + (size_t)tb*U_ + col,
                                   w3 + (size_t)tb*U_ + col };
            const int stra[4] = { D_, D_, U_, U_ };
            #pragma unroll
            for (int a = 0; a < 4; ++a)
                #pragma unroll
                for (int j = 0; j < 8; ++j) stg[a][j] = ga[a][(size_t)j * stra[a]];
        }
        // ---- fragment loads (ds_read_b128; group (5*row+lg)&7 even -> free)
        bf16x8 A1h[2], A1l[2], A2h[2], A2l[2];
        bf16x8 B2h[2], B2l[2], B3h[2], B3l[2];
        #pragma unroll
        for (int mi = 0; mi < 2; ++mi) {
            int off = (32*wd + 16*mi + lr)*LSTRIDE + 8*lg;
            A1h[mi] = *(const bf16x8*)&lds[0][off];
            A1l[mi] = *(const bf16x8*)&lds[1][off];
            A2h[mi] = *(const bf16x8*)&lds[2][off];
            A2l[mi] = *(const bf16x8*)&lds[3][off];
        }
        #pragma unroll
        for (int ni = 0; ni < 2; ++ni) {
            int off = (32*wu + 16*ni + lr)*LSTRIDE + 8*lg;
            B2h[ni] = *(const bf16x8*)&lds[4][off];
            B2l[ni] = *(const bf16x8*)&lds[5][off];
            B3h[ni] = *(const bf16x8*)&lds[6][off];
            B3l[ni] = *(const bf16x8*)&lds[7][off];
        }
        // ---- MFMA: 48 per wave per chunk
        #pragma unroll
        for (int mi = 0; mi < 2; ++mi)
            #pragma unroll
            for (int ni = 0; ni < 2; ++ni) {
                f32x4 c1 = acc1[mi][ni];
                f32x4 c2 = acc2[mi][ni];
                c1 = __builtin_amdgcn_mfma_f32_16x16x32_bf16(A1h[mi], B3h[ni], c1, 0, 0, 0);
                c1 = __builtin_amdgcn_mfma_f32_16x16x32_bf16(A1h[mi], B3l[ni], c1, 0, 0, 0);
                c1 = __builtin_amdgcn_mfma_f32_16x16x32_bf16(A1l[mi], B3h[ni], c1, 0, 0, 0);
                c1 = __builtin_amdgcn_mfma_f32_16x16x32_bf16(A2h[mi], B2h[ni], c1, 0, 0, 0);
                c1 = __builtin_amdgcn_mfma_f32_16x16x32_bf16(A2h[mi], B2l[ni], c1, 0, 0, 0);
                c1 = __builtin_amdgcn_mfma_f32_16x16x32_bf16(A2l[mi], B2h[ni], c1, 0, 0, 0);
                c2 = __builtin_amdgcn_mfma_f32_16x16x32_bf16(A1h[mi], B2h[ni], c2, 0, 0, 0);
                c2 = __builtin_amdgcn_mfma_f32_16x16x32_bf16(A1h[mi], B2l[ni], c2, 0, 0, 0);
                c2 = __builtin_amdgcn_mfma_f32_16x16x32_bf16(A1l[mi], B2h[ni], c2, 0, 0, 0);
                c2 = __builtin_amdgcn_mfma_f32_16x16x32_bf16(A2h[mi], B3h[ni], c2, 0, 0, 0);
                c2 = __builtin_amdgcn_mfma_f32_16x16x32_bf16(A2h[mi], B3l[ni], c2, 0, 0, 0);
                c2 = __builtin_amdgcn_mfma_f32_16x16x32_bf16(A2l[mi], B3h[ni], c2, 0, 0, 0);
                acc1[mi][ni] = c1;
                acc2[mi][ni] = c2;
            }
        __syncthreads();           // all waves done reading chunk c
        // ---- write next chunk (uint4, conflict-free groups)
        if (c+1 < NC_) {
            #pragma unroll
            for (int a = 0; a < 4; ++a) {
                uint4 hv, lv;
                pack8(stg[a], hv, lv);
                *(uint4*)&((uint*)lds[a*2  ])[widx] = hv;
                *(uint4*)&((uint*)lds[a*2+1])[widx] = lv;
            }
        }
        __syncthreads();           // writes visible for next iteration
    }

    // ---- epilogue: C/D layout col=lane&15, row=(lane>>4)*4+reg
    const size_t DU = (size_t)D_ * U_;
    const size_t base0 = (((size_t)ts*B_ + b)*2)*DU;
    #pragma unroll
    for (int mi = 0; mi < 2; ++mi)
        #pragma unroll
        for (int ni = 0; ni < 2; ++ni) {
            const int d = d0 + 32*wd + 16*mi + 4*lg;
            const int u = 32*wu + 16*ni + lr;
            #pragma unroll
            for (int r = 0; r < 4; ++r) {
                P[base0 + (size_t)(d+r)*U_ + u]      = acc1[mi][ni][r];
                P[base0 + DU + (size_t)(d+r)*U_ + u] = acc2[mi][ni][r];
            }
        }
}

// ---------------------------------------------------------------------------
// K1b: M1 = w1 + sum_ts P[ts][b][0];  M2 = w1 + sum_ts P[ts][b][1]
// ---------------------------------------------------------------------------
__global__ __launch_bounds__(256) void k1_combine(
    const float* __restrict__ P, const float* __restrict__ w1,
    float* __restrict__ M1, float* __restrict__ M2)
{
    const int n = blockIdx.x*256 + threadIdx.x;   // 0 .. B*D*U/4-1
    const int b = n >> 13;                        // D*U/4 = 8192
    const int r = n & 8191;
    const size_t du = (size_t)r * 4;
    const size_t DU = (size_t)D_ * U_;
    float4 w = *(const float4*)&w1[du];
    float4 s1 = w, s2 = w;
    #pragma unroll
    for (int ts = 0; ts < TS_; ++ts) {
        const float* Pb = P + (((size_t)ts*B_ + b)*2)*DU + du;
        float4 a = *(const float4*)&Pb[0];
        float4 c = *(const float4*)&Pb[DU];
        s1.x += a.x; s1.y += a.y; s1.z += a.z; s1.w += a.w;
        s2.x += c.x; s2.y += c.y; s2.z += c.z; s2.w += c.w;
    }
    *(float4*)&M1[(size_t)b*DU + du] = s1;
    *(float4*)&M2[(size_t)b*DU + du] = s2;
}

// ---------------------------------------------------------------------------
// K2 (MFMA): eij[br][b][t] = SR * sum_u tanh( H[t,u] ) * we[u],
//   H = x[b] @ M[br][b]. bf16-split 3-term; XOR swizzle on both tiles.
// STAGING WRITES uint4: x thread mapping (t=tid>>2, dblk=tid&3, 16 d) gives
// 2 uint4/plane at group (2*dblk+q)^(t&7) (even); M at group (2*dq+q)^(u&7).
// (Old b32 writes: M 8-way, x 4-way bank conflicts.) Reads unchanged.
// ---------------------------------------------------------------------------
__global__ __launch_bounds__(256, 4) void k2_eij(
    const float* __restrict__ x1, const float* __restrict__ x2,
    const float* __restrict__ M1, const float* __restrict__ M2,
    const float* __restrict__ we, float* __restrict__ eij)
{
    __shared__ ushort xh[64*64];   // 8 KiB each; 32 KiB total
    __shared__ ushort xl[64*64];
    __shared__ ushort mh[64*64];
    __shared__ ushort ml[64*64];

    const int tt = blockIdx.x;       // 0..15
    const int b  = blockIdx.y;       // 0..31
    const int br = blockIdx.z;       // 0..1
    const float* x = br ? x2 : x1;
    const float* M = (br ? M2 : M1) + (size_t)b * D_ * U_;
    const int tid  = threadIdx.x;
    const int lane = tid & 63;
    const int wid  = tid >> 6;       // wave -> t-row block (16 rows)
    const int lr   = lane & 15;
    const int lg   = lane >> 4;

    const int s_t  = tid >> 2;       // 0..63 : t row (x stage)
    const int s_db = tid & 3;        // 16-d block within 64-d chunk
    const int m_u  = tid & 63;       // u column (M stage)
    const int m_dq = tid >> 6;       // 0..3 : 16-d slice

    f32x4 acc[4];
    const f32x4 z = {0.f, 0.f, 0.f, 0.f};
    #pragma unroll
    for (int ni = 0; ni < 4; ++ni) acc[ni] = z;

    float wreg[4];
    #pragma unroll
    for (int ni = 0; ni < 4; ++ni) wreg[ni] = we[ni*16 + lr];

    const size_t xbase = ((size_t)b*T_ + (size_t)tt*64) * D_;
    const int xswz = (s_t & 7) << 2;
    const int mswz = (m_u & 7) << 2;

    float4 sx[4];     // staged x: 16 consecutive d of one t
    float  sm[16];    // staged M: 16 consecutive d of one u

    // ---- issue + write chunk 0
    #pragma unroll
    for (int k = 0; k < 4; ++k)
        sx[k] = *(const float4*)&x[xbase + (size_t)s_t*D_ + s_db*16 + 4*k];
    #pragma unroll
    for (int j2 = 0; j2 < 16; ++j2)
        sm[j2] = M[(size_t)(m_dq*16 + j2)*U_ + m_u];
    {
        uint4 hv, lv;
        pack8(&sx[0].x, hv, lv);     // d-pairs s_db*8 .. +3
        *(uint4*)&((uint*)xh)[s_t*32 + ((s_db*8    ) ^ xswz)] = hv;
        *(uint4*)&((uint*)xl)[s_t*32 + ((s_db*8    ) ^ xswz)] = lv;
        pack8(&sx[2].x, hv, lv);     // d-pairs s_db*8+4 .. +7
        *(uint4*)&((uint*)xh)[s_t*32 + ((s_db*8 + 4) ^ xswz)] = hv;
        *(uint4*)&((uint*)xl)[s_t*32 + ((s_db*8 + 4) ^ xswz)] = lv;
        pack8(&sm[0], hv, lv);
        *(uint4*)&((uint*)mh)[m_u*32 + ((m_dq*8    ) ^ mswz)] = hv;
        *(uint4*)&((uint*)ml)[m_u*32 + ((m_dq*8    ) ^ mswz)] = lv;
        pack8(&sm[8], hv, lv);
        *(uint4*)&((uint*)mh)[m_u*32 + ((m_dq*8 + 4) ^ mswz)] = hv;
        *(uint4*)&((uint*)ml)[m_u*32 + ((m_dq*8 + 4) ^ mswz)] = lv;
    }
    __syncthreads();

    for (int c = 0; c < D_/64; ++c) {
        // ---- issue next chunk's loads
        if (c+1 < D_/64) {
            const int d1 = (c+1)*64;
            #pragma unroll
            for (int k = 0; k < 4; ++k)
                sx[k] = *(const float4*)&x[xbase + (size_t)s_t*D_ + d1 + s_db*16 + 4*k];
            #pragma unroll
            for (int j2 = 0; j2 < 16; ++j2)
                sm[j2] = M[(size_t)(d1 + m_dq*16 + j2)*U_ + m_u];
        }
        // ---- MFMA: per wave 2 kk x 4 ni x 3 = 24 per chunk
        #pragma unroll
        for (int kk = 0; kk < 2; ++kk) {
            const int ar   = wid*16 + lr;
            const int aoff = ar*64 + (((lg + 4*kk)*8) ^ ((ar & 7) << 3));
            bf16x8 Ah = *(const bf16x8*)&xh[aoff];
            bf16x8 Al = *(const bf16x8*)&xl[aoff];
            #pragma unroll
            for (int ni = 0; ni < 4; ++ni) {
                const int bu   = ni*16 + lr;
                const int boff = bu*64 + (((lg + 4*kk)*8) ^ ((bu & 7) << 3));
                bf16x8 Bh = *(const bf16x8*)&mh[boff];
                bf16x8 Bl = *(const bf16x8*)&ml[boff];
                f32x4 a = acc[ni];
                a = __builtin_amdgcn_mfma_f32_16x16x32_bf16(Ah, Bh, a, 0, 0, 0);
                a = __builtin_amdgcn_mfma_f32_16x16x32_bf16(Ah, Bl, a, 0, 0, 0);
                a = __builtin_amdgcn_mfma_f32_16x16x32_bf16(Al, Bh, a, 0, 0, 0);
                acc[ni] = a;
            }
        }
        __syncthreads();           // all waves done reading chunk c
        // ---- write next chunk (uint4, conflict-free groups)
        if (c+1 < D_/64) {
            uint4 hv, lv;
            pack8(&sx[0].x, hv, lv);
            *(uint4*)&((uint*)xh)[s_t*32 + ((s_db*8    ) ^ xswz)] = hv;
            *(uint4*)&((uint*)xl)[s_t*32 + ((s_db*8    ) ^ xswz)] = lv;
            pack8(&sx[2].x, hv, lv);
            *(uint4*)&((uint*)xh)[s_t*32 + ((s_db*8 + 4) ^ xswz)] = hv;
            *(uint4*)&((uint*)xl)[s_t*32 + ((s_db*8 + 4) ^ xswz)] = lv;
            pack8(&sm[0], hv, lv);
            *(uint4*)&((uint*)mh)[m_u*32 + ((m_dq*8    ) ^ mswz)] = hv;
            *(uint4*)&((uint*)ml)[m_u*32 + ((m_dq*8    ) ^ mswz)] = lv;
            pack8(&sm[8], hv, lv);
            *(uint4*)&((uint*)mh)[m_u*32 + ((m_dq*8 + 4) ^ mswz)] = hv;
            *(uint4*)&((uint*)ml)[m_u*32 + ((m_dq*8 + 4) ^ mswz)] = lv;
        }
        __syncthreads();           // writes visible for next iteration
    }

    // ---- epilogue: row=(lane>>4)*4+r, col=ni*16+lr
    #pragma unroll
    for (int r = 0; r < 4; ++r) {
        float s = 0.f;
        #pragma unroll
        for (int ni = 0; ni < 4; ++ni) s += tanhf(acc[ni][r]) * wreg[ni];
        s += __shfl_xor(s, 1);
        s += __shfl_xor(s, 2);
        s += __shfl_xor(s, 4);
        s += __shfl_xor(s, 8);
        if (lr == 0) {
            int t = tt*64 + wid*16 + lg*4 + r;
            eij[((size_t)br*B_ + b)*T_ + t] = SR_ * s;
        }
    }
}

// ---------------------------------------------------------------------------
// K45: fused softmax + scale (unchanged).
// ---------------------------------------------------------------------------
__global__ __launch_bounds__(256) void k45_scale(
    const float* __restrict__ x1, const float* __restrict__ x2,
    const float* __restrict__ eij, float* __restrict__ out)
{
    __shared__ float sdata[256];
    __shared__ float wws[T_];

    const int tt = blockIdx.x;       // 0..15 : t-chunk of 64
    const int b  = blockIdx.y;       // 0..31
    const int br = blockIdx.z;       // 0..1
    const int tid = threadIdx.x;
    const float* e = eij + ((size_t)br*B_ + b) * T_;

    float v[4];
    float m = -1e30f;
    #pragma unroll
    for (int i = 0; i < 4; ++i) { v[i] = e[tid + i*256]; m = fmaxf(m, v[i]); }
    sdata[tid] = m; __syncthreads();
    for (int s = 128; s > 0; s >>= 1) {
        if (tid < s) sdata[tid] = fmaxf(sdata[tid], sdata[tid+s]);
        __syncthreads();
    }
    m = sdata[0]; __syncthreads();
    float ssum = 0.f;
    #pragma unroll
    for (int i = 0; i < 4; ++i) { v[i] = expf(v[i] - m); ssum += v[i]; }
    sdata[tid] = ssum; __syncthreads();
    for (int s = 128; s > 0; s >>= 1) {
        if (tid < s) sdata[tid] += sdata[tid+s];
        __syncthreads();
    }
    const float inv = 1.0f / (sdata[0] + EPS_ * expf(-m));
    #pragma unroll
    for (int i = 0; i < 4; ++i) wws[tid + i*256] = v[i] * inv;
    __syncthreads();

    const float* x = br ? x2 : x1;
    const size_t xb4 = ((size_t)b*T_ + (size_t)tt*64) * (D_/4);
    float* o = out + (size_t)br*B_*T_*D_;
    #pragma unroll
    for (int k = 0; k < 32; ++k) {
        int idx = k*256 + tid;           // 0..8191
        int tl  = idx >> 7;              // 0..63
        float w = wws[tt*64 + tl];
        float4 xv = ((const float4*)x)[xb4 + idx];
        float4 ov = {xv.x*w, xv.y*w, xv.z*w, xv.w*w};
        ((float4*)o)[xb4 + idx] = ov;
    }
}

// ---------------------------------------------------------------------------
extern "C" void kernel_launch(void* const* d_in, const int* in_sizes, int n_in,
                              void* d_out, int out_size, void* d_ws, size_t ws_size,
                              hipStream_t stream)
{
    const float* x1 = (const float*)d_in[0];
    const float* x2 = (const float*)d_in[1];
    const float* w1 = (const float*)d_in[2];
    const float* w2 = (const float*)d_in[3];
    const float* w3 = (const float*)d_in[4];
    const float* we = (const float*)d_in[5];
    float* out = (float*)d_out;
    float* ws  = (float*)d_ws;

    // workspace layout (floats)
    float* P   = ws;                             // TS_*B_*2*D_*U_ = 8,388,608
    float* M1  = P   + (size_t)TS_*B_*2*D_*U_;   // 1,048,576
    float* M2  = M1  + (size_t)B_*D_*U_;         // 1,048,576
    float* eij = M2  + (size_t)B_*D_*U_;         // 65,536

    k1_partials<<<dim3(8, TS_, B_), 256, 0, stream>>>(x1, x2, w2, w3, P);
    k1_combine <<<dim3((B_*D_*U_/4 + 255)/256), 256, 0, stream>>>(P, w1, M1, M2);
    k2_eij     <<<dim3(T_/TT_, B_, 2), 256, 0, stream>>>(x1, x2, M1, M2, we, eij);
    k45_scale  <<<dim3(16, B_, 2), 256, 0, stream>>>(x1, x2, eij, out);
}